// Round 4
// baseline (742.740 us; speedup 1.0000x reference)
//
#include <hip/hip_runtime.h>

// ============================================================================
// SEB_59201829208446 round 7:
//   - conv_k v3: M-tile 64, K-split 2 (z = z0 + z1), grid (7, 8, 32) = 1792
//     blocks = 7168 waves = 7 waves/SIMD (rounds 5/6 both had 1792 waves =
//     1.75/SIMD -> latency-bound at 8% MfmaUtil). 24 KB LDS.
//   - conv B-staging: per-thread 8k x 4n with k-octet chunks -> LDS write
//     conflicts ~16-way -> ~4-way, half the write instructions.
//   - bn_stats/bn_apply sum z0+z1 (BN z-traffic doubles, ~+10 us, vs ~-70 us
//     in conv).
//   - everything else unchanged from round 6 (739 us; conv was 147 us).
// 24 launches.
// ============================================================================

typedef unsigned short u16;
typedef __attribute__((ext_vector_type(8))) short bf16x8;
typedef __attribute__((ext_vector_type(4))) float f32x4;

__device__ __forceinline__ u16 f2bf(float f) {
  unsigned u = __builtin_bit_cast(unsigned, f);
  u += 0x7FFFu + ((u >> 16) & 1u);
  return (u16)(u >> 16);
}
__device__ __forceinline__ float bf2f(u16 h) {
  unsigned u = ((unsigned)h) << 16;
  return __builtin_bit_cast(float, u);
}

// ---------------------------------------------------------------------------
// Core 128x128x256 split-bf16 tile compute (B must be symmetric).
// ---------------------------------------------------------------------------
__device__ __forceinline__
void mm_core(const u16* __restrict__ Ah, const u16* __restrict__ Al,
             const u16* __restrict__ Bh, const u16* __restrict__ Bl,
             long boff, int row0, int col0,
             u16 (*lds)[128][8][8], f32x4 acc[4][4])
{
  const int tid = threadIdx.x;
  const int wave = tid >> 6, lane = tid & 63;
  const int wm = wave >> 1, wn = wave & 1;
  const int mL = lane & 15, q = lane >> 4;
  const u16* baseA[2] = {Ah + boff, Al + boff};
  const u16* baseB[2] = {Bh + boff, Bl + boff};

  for (int k0 = 0; k0 < 256; k0 += 64) {
    __syncthreads();
#pragma unroll
    for (int it = 0; it < 16; ++it) {
      const int t = it >> 2;                    // 0:Ah 1:Al 2:Bh 3:Bl
      const int r = ((it & 3) << 8) + tid;
      const int m = r >> 3, c = r & 7;
      const u16* src = (t < 2 ? baseA[t] : baseB[t - 2])
                     + (long)((t < 2 ? row0 : col0) + m) * 256 + k0 + c * 8;
      const uint4 v = *reinterpret_cast<const uint4*>(src);
      *reinterpret_cast<uint4*>(&lds[t][m][c ^ (m & 7)][0]) = v;
    }
    __syncthreads();
#pragma unroll
    for (int kk = 0; kk < 2; ++kk) {
      bf16x8 ah[4], al[4], bh[4], bl[4];
#pragma unroll
      for (int i = 0; i < 4; ++i) {
        const int ma = wm * 64 + i * 16 + mL;
        const int ca = (kk * 4 + q) ^ (ma & 7);
        ah[i] = *reinterpret_cast<const bf16x8*>(&lds[0][ma][ca][0]);
        al[i] = *reinterpret_cast<const bf16x8*>(&lds[1][ma][ca][0]);
        const int nb = wn * 64 + i * 16 + mL;
        const int cb = (kk * 4 + q) ^ (nb & 7);
        bh[i] = *reinterpret_cast<const bf16x8*>(&lds[2][nb][cb][0]);
        bl[i] = *reinterpret_cast<const bf16x8*>(&lds[3][nb][cb][0]);
      }
#pragma unroll
      for (int i = 0; i < 4; ++i)
#pragma unroll
        for (int j = 0; j < 4; ++j) {
          acc[i][j] = __builtin_amdgcn_mfma_f32_16x16x32_bf16(ah[i], bh[j], acc[i][j], 0, 0, 0);
          acc[i][j] = __builtin_amdgcn_mfma_f32_16x16x32_bf16(ah[i], bl[j], acc[i][j], 0, 0, 0);
          acc[i][j] = __builtin_amdgcn_mfma_f32_16x16x32_bf16(al[i], bh[j], acc[i][j], 0, 0, 0);
        }
    }
  }
}

// ---------------------------------------------------------------------------
// Dual-task fused GEMM launch: z<32 -> task0 (MODE0 epilogue);
// z>=32 -> task1 (MODE0 if MB==0, MODE1 dual-out if MB==1).
// MODE0: C = al*(A@B) + b1*cf + dg*I (split out)
// MODE1: C = A@B raw; D = C*hc1 + cf*hc2 + hc3*I
// ---------------------------------------------------------------------------
template<int MB>
__global__ __launch_bounds__(256)
void fuse_k(const u16* __restrict__ A0, const u16* __restrict__ B0, u16* __restrict__ C0,
            float al0, float b10, float dg0, const float* __restrict__ cf0,
            const u16* __restrict__ A1, const u16* __restrict__ B1, u16* __restrict__ C1,
            u16* __restrict__ D1, float al1, float b11, float dg1,
            float hc1, float hc2, float hc3, const float* __restrict__ cf1, long LO)
{
  __shared__ u16 lds[4][128][8][8];
  int z = blockIdx.z;
  const bool hB = (z >= 32);
  const u16 *Ah, *Bh; u16 *C, *D = nullptr;
  float al, b1, dg; const float* cf;
  if (!hB) { Ah = A0; Bh = B0; C = C0; al = al0; b1 = b10; dg = dg0; cf = cf0; }
  else { z -= 32; Ah = A1; Bh = B1; C = C1; D = D1; al = al1; b1 = b11; dg = dg1; cf = cf1; }
  const long boff = (long)z * 65536;
  const int row0 = blockIdx.y * 128, col0 = blockIdx.x * 128;
  const int wave = threadIdx.x >> 6, lane = threadIdx.x & 63;
  const int wm = wave >> 1, wn = wave & 1;
  const int mL = lane & 15, q = lane >> 4;

  f32x4 acc[4][4];
#pragma unroll
  for (int i = 0; i < 4; ++i)
#pragma unroll
    for (int j = 0; j < 4; ++j) acc[i][j] = {0.f, 0.f, 0.f, 0.f};

  mm_core(Ah, Ah + LO, Bh, Bh + LO, boff, row0, col0, lds, acc);

#pragma unroll
  for (int i = 0; i < 4; ++i) {
    const int rbase = row0 + wm * 64 + i * 16 + q * 4;
#pragma unroll
    for (int j = 0; j < 4; ++j) {
      const int cc = col0 + wn * 64 + j * 16 + mL;
#pragma unroll
      for (int rg = 0; rg < 4; ++rg) {
        const int rr = rbase + rg;
        const long o = boff + (long)rr * 256 + cc;
        const float vr = acc[i][j][rg];
        if (MB == 1 && hB) {
          u16 h = f2bf(vr);
          C[o] = h; C[o + LO] = f2bf(vr - bf2f(h));
          float hv = fmaf(vr, hc1, cf[o] * hc2);
          if (rr == cc) hv += hc3;
          h = f2bf(hv);
          D[o] = h; D[o + LO] = f2bf(hv - bf2f(h));
        } else {
          float v = al * vr;
          if (cf) v = fmaf(b1, cf[o], v);
          if (rr == cc) v += dg;
          const u16 h = f2bf(v);
          C[o] = h; C[o + LO] = f2bf(v - bf2f(h));
        }
      }
    }
  }
}

// Fused pair: z<32 -> C0 = A0@B0 ; z>=32 -> C1 = A1@B1 (both plain, alpha=1)
__global__ __launch_bounds__(256)
void gemm2_pair_k(const u16* __restrict__ A0, const u16* __restrict__ B0, u16* __restrict__ C0,
                  const u16* __restrict__ A1, const u16* __restrict__ B1, u16* __restrict__ C1,
                  long LO)
{
  __shared__ u16 lds[4][128][8][8];
  int z = blockIdx.z;
  const u16 *Ah, *Bh; u16* Chp;
  if (z < 32) { Ah = A0; Bh = B0; Chp = C0; }
  else { z -= 32; Ah = A1; Bh = B1; Chp = C1; }
  const long boff = (long)z * 65536;
  const int row0 = blockIdx.y * 128, col0 = blockIdx.x * 128;
  const int wave = threadIdx.x >> 6, lane = threadIdx.x & 63;
  const int wm = wave >> 1, wn = wave & 1;
  const int mL = lane & 15, q = lane >> 4;

  f32x4 acc[4][4];
#pragma unroll
  for (int i = 0; i < 4; ++i)
#pragma unroll
    for (int j = 0; j < 4; ++j) acc[i][j] = {0.f, 0.f, 0.f, 0.f};

  mm_core(Ah, Ah + LO, Bh, Bh + LO, boff, row0, col0, lds, acc);

#pragma unroll
  for (int i = 0; i < 4; ++i) {
    const int rbase = row0 + wm * 64 + i * 16 + q * 4;
#pragma unroll
    for (int j = 0; j < 4; ++j) {
      const int cc = col0 + wn * 64 + j * 16 + mL;
#pragma unroll
      for (int rg = 0; rg < 4; ++rg) {
        const long o = boff + (long)(rbase + rg) * 256 + cc;
        const float v = acc[i][j][rg];
        const u16 h = f2bf(v);
        Chp[o] = h; Chp[o + LO] = f2bf(v - bf2f(h));
      }
    }
  }
}

// ---------------------------------------------------------------------------
// 128x64-tile split GEMM, grid (4,2,32)=256 blocks -> full CU coverage.
// MODE 0: C = alpha*(A@B) + b1*cf + diag*I (split out)
// MODE 2: no write; atomicAdd(attn2[z], ||A@B||_F^2 partial)
// ---------------------------------------------------------------------------
template<int MODE>
__global__ __launch_bounds__(256)
void gemmN64_k(const u16* __restrict__ Ah, const u16* __restrict__ Al,
               const u16* __restrict__ Bh, const u16* __restrict__ Bl,
               u16* __restrict__ Ch, u16* __restrict__ Cl,
               const float* __restrict__ cf, float alpha, float b1, float diag,
               float* __restrict__ attn2)
{
  __shared__ u16 ldsA[2][128][8][8];
  __shared__ u16 ldsB[2][64][8][8];
  const long boff = (long)blockIdx.z * 65536;
  const int row0 = blockIdx.y * 128, col0 = blockIdx.x * 64;
  const int tid = threadIdx.x;
  const int wave = tid >> 6, lane = tid & 63;
  const int wm = wave >> 1, wn = wave & 1;
  const int mL = lane & 15, q = lane >> 4;
  const u16* baseA[2] = {Ah + boff, Al + boff};
  const u16* baseB[2] = {Bh + boff, Bl + boff};

  f32x4 acc[4][2];
#pragma unroll
  for (int i = 0; i < 4; ++i)
#pragma unroll
    for (int j = 0; j < 2; ++j) acc[i][j] = {0.f, 0.f, 0.f, 0.f};

  for (int k0 = 0; k0 < 256; k0 += 64) {
    __syncthreads();
#pragma unroll
    for (int it = 0; it < 8; ++it) {           // A: 2 planes x 4 its
      const int t = it >> 2;
      const int r = ((it & 3) << 8) + tid;
      const int m = r >> 3, c = r & 7;
      const uint4 v = *reinterpret_cast<const uint4*>(
          baseA[t] + (long)(row0 + m) * 256 + k0 + c * 8);
      *reinterpret_cast<uint4*>(&ldsA[t][m][c ^ (m & 7)][0]) = v;
    }
#pragma unroll
    for (int it = 0; it < 4; ++it) {           // B: 2 planes x 2 its
      const int t = it >> 1;
      const int r = ((it & 1) << 8) + tid;
      const int m = r >> 3, c = r & 7;
      const uint4 v = *reinterpret_cast<const uint4*>(
          baseB[t] + (long)(col0 + m) * 256 + k0 + c * 8);
      *reinterpret_cast<uint4*>(&ldsB[t][m][c ^ (m & 7)][0]) = v;
    }
    __syncthreads();
#pragma unroll
    for (int kk = 0; kk < 2; ++kk) {
      bf16x8 ah[4], alo[4], bh[2], bl[2];
#pragma unroll
      for (int i = 0; i < 4; ++i) {
        const int ma = wm * 64 + i * 16 + mL;
        const int ca = (kk * 4 + q) ^ (ma & 7);
        ah[i]  = *reinterpret_cast<const bf16x8*>(&ldsA[0][ma][ca][0]);
        alo[i] = *reinterpret_cast<const bf16x8*>(&ldsA[1][ma][ca][0]);
      }
#pragma unroll
      for (int j = 0; j < 2; ++j) {
        const int nb = wn * 32 + j * 16 + mL;
        const int cb = (kk * 4 + q) ^ (nb & 7);
        bh[j] = *reinterpret_cast<const bf16x8*>(&ldsB[0][nb][cb][0]);
        bl[j] = *reinterpret_cast<const bf16x8*>(&ldsB[1][nb][cb][0]);
      }
#pragma unroll
      for (int i = 0; i < 4; ++i)
#pragma unroll
        for (int j = 0; j < 2; ++j) {
          acc[i][j] = __builtin_amdgcn_mfma_f32_16x16x32_bf16(ah[i],  bh[j], acc[i][j], 0, 0, 0);
          acc[i][j] = __builtin_amdgcn_mfma_f32_16x16x32_bf16(ah[i],  bl[j], acc[i][j], 0, 0, 0);
          acc[i][j] = __builtin_amdgcn_mfma_f32_16x16x32_bf16(alo[i], bh[j], acc[i][j], 0, 0, 0);
        }
    }
  }

  if (MODE == 2) {
    float ssum = 0.f;
#pragma unroll
    for (int i = 0; i < 4; ++i)
#pragma unroll
      for (int j = 0; j < 2; ++j)
#pragma unroll
        for (int rg = 0; rg < 4; ++rg) ssum = fmaf(acc[i][j][rg], acc[i][j][rg], ssum);
#pragma unroll
    for (int o = 32; o > 0; o >>= 1) ssum += __shfl_down(ssum, o);
    __syncthreads();
    float* red = (float*)&ldsA[0][0][0][0];
    if (lane == 0) red[wave] = ssum;
    __syncthreads();
    if (tid == 0)
      atomicAdd(attn2 + blockIdx.z, red[0] + red[1] + red[2] + red[3]);
    return;
  }

#pragma unroll
  for (int i = 0; i < 4; ++i) {
    const int rbase = row0 + wm * 64 + i * 16 + q * 4;
#pragma unroll
    for (int j = 0; j < 2; ++j) {
      const int cc = col0 + wn * 32 + j * 16 + mL;
#pragma unroll
      for (int rg = 0; rg < 4; ++rg) {
        const int rr = rbase + rg;
        const long o = boff + (long)rr * 256 + cc;
        float v = alpha * acc[i][j][rg];
        if (cf) v = fmaf(b1, cf[o], v);
        if (rr == cc) v += diag;
        const u16 h = f2bf(v);
        Ch[o] = h; Cl[o] = f2bf(v - bf2f(h));
      }
    }
  }
}

// ---------------------------------------------------------------------------
// conv1x1 v3: z[b] = W(256x2048) @ x_b(2048x784). M-tile 64, K-split 2:
// grid (7, 4m x 2ks, 32) = 1792 blocks, 256 thr = 7168 waves = 7/SIMD.
// ks=0 -> z0, ks=1 -> z1 (BN sums them). 24 KB LDS.
// ---------------------------------------------------------------------------
__global__ __launch_bounds__(256)
void conv_k(const u16* __restrict__ wb, const float* __restrict__ x,
            float* __restrict__ z0, float* __restrict__ z1)
{
  __shared__ u16 ldsA[64][8][8];    // 8 KB: W rows m0..m0+63
  __shared__ u16 ldsB[128][8][8];   // 16 KB: x cols n0..n0+127 (as rows)
  const int tid = threadIdx.x;
  const int b = blockIdx.z;
  const int n0 = blockIdx.x * 128;
  const int m0 = (blockIdx.y & 3) * 64;
  const int ks = blockIdx.y >> 2;
  const int kb0 = ks * 1024;
  const int wave = tid >> 6, lane = tid & 63;
  const int wm = wave >> 1, wn = wave & 1;
  const int mL = lane & 15, q = lane >> 4;
  const float* xb = x + (long)b * 2048 * 784;
  float* zp = (ks == 0 ? z0 : z1);

  f32x4 acc[2][4];
#pragma unroll
  for (int i = 0; i < 2; ++i)
#pragma unroll
    for (int j = 0; j < 4; ++j) acc[i][j] = {0.f, 0.f, 0.f, 0.f};

  const int kc = tid >> 5, nc = tid & 31;     // kc 0..7 (k-octet), nc 0..31
  const int nbase = nc * 4;
  const int gn = n0 + nbase;

  for (int k0 = 0; k0 < 1024; k0 += 64) {
    const int kg = kb0 + k0;
    __syncthreads();
    // A: 64 rows x 8 chunks = 512 slots of 8 bf16; 2 per thread
#pragma unroll
    for (int it = 0; it < 2; ++it) {
      const int g = it * 256 + tid;
      const int m = g >> 3, c = g & 7;
      const uint4 v = *reinterpret_cast<const uint4*>(
          wb + (long)(m0 + m) * 2048 + kg + c * 8);
      *reinterpret_cast<uint4*>(&ldsA[m][c ^ (m & 7)][0]) = v;
    }
    // B: thread covers k = kg+kc*8 .. +7, n = nbase .. +3
    {
      float vv[8][4];
#pragma unroll
      for (int jk = 0; jk < 8; ++jk) {
        float4 f = make_float4(0.f, 0.f, 0.f, 0.f);
        if (gn < 784)
          f = *reinterpret_cast<const float4*>(xb + (long)(kg + kc * 8 + jk) * 784 + gn);
        vv[jk][0] = f.x; vv[jk][1] = f.y; vv[jk][2] = f.z; vv[jk][3] = f.w;
      }
#pragma unroll
      for (int jn = 0; jn < 4; ++jn) {
        const int n = nbase + jn;
        const int ch = kc ^ (n & 7);
        ushort4 ua, ub;
        ua.x = f2bf(vv[0][jn]); ua.y = f2bf(vv[1][jn]);
        ua.z = f2bf(vv[2][jn]); ua.w = f2bf(vv[3][jn]);
        ub.x = f2bf(vv[4][jn]); ub.y = f2bf(vv[5][jn]);
        ub.z = f2bf(vv[6][jn]); ub.w = f2bf(vv[7][jn]);
        *reinterpret_cast<ushort4*>(&ldsB[n][ch][0]) = ua;
        *reinterpret_cast<ushort4*>(&ldsB[n][ch][4]) = ub;
      }
    }
    __syncthreads();
#pragma unroll
    for (int kk = 0; kk < 2; ++kk) {
      bf16x8 af[2], bfv[4];
#pragma unroll
      for (int i = 0; i < 2; ++i) {
        const int ma = wm * 32 + i * 16 + mL;
        af[i] = *reinterpret_cast<const bf16x8*>(&ldsA[ma][(kk * 4 + q) ^ (ma & 7)][0]);
      }
#pragma unroll
      for (int j = 0; j < 4; ++j) {
        const int nb = wn * 64 + j * 16 + mL;
        bfv[j] = *reinterpret_cast<const bf16x8*>(&ldsB[nb][(kk * 4 + q) ^ (nb & 7)][0]);
      }
#pragma unroll
      for (int i = 0; i < 2; ++i)
#pragma unroll
        for (int j = 0; j < 4; ++j)
          acc[i][j] = __builtin_amdgcn_mfma_f32_16x16x32_bf16(af[i], bfv[j], acc[i][j], 0, 0, 0);
    }
  }
#pragma unroll
  for (int i = 0; i < 2; ++i) {
    const int rbase = m0 + wm * 32 + i * 16 + q * 4;
#pragma unroll
    for (int j = 0; j < 4; ++j) {
      const int cc = n0 + wn * 64 + j * 16 + mL;
      if (cc >= 784) continue;
#pragma unroll
      for (int rg = 0; rg < 4; ++rg)
        zp[((long)b * 256 + rbase + rg) * 784 + cc] = acc[i][j][rg];
    }
  }
}

// ---------------------------------------------------------------------------
// Gram: cov[b] = (1/784) zb@zb^T - mu mu^T; also writes C2 = split(cov).
// ---------------------------------------------------------------------------
__global__ __launch_bounds__(256)
void gram_k(const u16* __restrict__ zb, const float* __restrict__ rs,
            float* __restrict__ cov, u16* __restrict__ C2h, u16* __restrict__ C2l)
{
  __shared__ u16 lds[2][128][8][8];
  const int tid = threadIdx.x;
  const int b = blockIdx.z;
  const int col0 = blockIdx.x * 128, row0 = blockIdx.y * 128;
  const int wave = tid >> 6, lane = tid & 63;
  const int wm = wave >> 1, wn = wave & 1;
  const int mL = lane & 15, q = lane >> 4;
  const u16* zbb = zb + (long)b * 256 * 832;

  f32x4 acc[4][4];
#pragma unroll
  for (int i = 0; i < 4; ++i)
#pragma unroll
    for (int j = 0; j < 4; ++j) acc[i][j] = {0.f, 0.f, 0.f, 0.f};

  for (int k0 = 0; k0 < 832; k0 += 64) {
    __syncthreads();
#pragma unroll
    for (int it = 0; it < 8; ++it) {
      const int t = it >> 2;
      const int r = ((it & 3) << 8) + tid;
      const int m = r >> 3, c = r & 7;
      const int grow = (t == 0 ? row0 : col0) + m;
      const uint4 v = *reinterpret_cast<const uint4*>(zbb + (long)grow * 832 + k0 + c * 8);
      *reinterpret_cast<uint4*>(&lds[t][m][c ^ (m & 7)][0]) = v;
    }
    __syncthreads();
#pragma unroll
    for (int kk = 0; kk < 2; ++kk) {
      bf16x8 af[4], bfv[4];
#pragma unroll
      for (int i = 0; i < 4; ++i) {
        const int ma = wm * 64 + i * 16 + mL;
        af[i] = *reinterpret_cast<const bf16x8*>(&lds[0][ma][(kk * 4 + q) ^ (ma & 7)][0]);
        const int nb = wn * 64 + i * 16 + mL;
        bfv[i] = *reinterpret_cast<const bf16x8*>(&lds[1][nb][(kk * 4 + q) ^ (nb & 7)][0]);
      }
#pragma unroll
      for (int i = 0; i < 4; ++i)
#pragma unroll
        for (int j = 0; j < 4; ++j)
          acc[i][j] = __builtin_amdgcn_mfma_f32_16x16x32_bf16(af[i], bfv[j], acc[i][j], 0, 0, 0);
    }
  }
  const float inv_m = 1.f / 784.f;
#pragma unroll
  for (int i = 0; i < 4; ++i) {
    const int rr0 = row0 + wm * 64 + i * 16 + q * 4;
#pragma unroll
    for (int j = 0; j < 4; ++j) {
      const int cc = col0 + wn * 64 + j * 16 + mL;
      const float mu_c = rs[b * 256 + cc] * inv_m;
#pragma unroll
      for (int rg = 0; rg < 4; ++rg) {
        const int rr = rr0 + rg;
        const float mu_r = rs[b * 256 + rr] * inv_m;
        const long o = ((long)b * 256 + rr) * 256 + cc;
        const float cv = fmaf(acc[i][j][rg], inv_m, -mu_r * mu_c);
        cov[o] = cv;
        const u16 h = f2bf(cv);
        C2h[o] = h; C2l[o] = f2bf(cv - bf2f(h));
      }
    }
  }
}

// ---- BN pass 1: partial sums/sumsq per (channel, batch-slice of 4) --------
__global__ __launch_bounds__(256)
void bn_stats_k(const float* __restrict__ z0, const float* __restrict__ z1,
                float* __restrict__ ps, float* __restrict__ pq)
{
  const int d = blockIdx.x, sl = blockIdx.y, t = threadIdx.x;
  const int lane = t & 63, wid = t >> 6;
  __shared__ float ws[4], wq[4];
  float s = 0.f, qq = 0.f;
  for (int b = sl * 4; b < sl * 4 + 4; ++b) {
    const long off = ((long)b * 256 + d) * 784;
    for (int m = t; m < 784; m += 256) {
      const float v = z0[off + m] + z1[off + m];
      s += v; qq = fmaf(v, v, qq);
    }
  }
#pragma unroll
  for (int o = 32; o > 0; o >>= 1) { s += __shfl_down(s, o); qq += __shfl_down(qq, o); }
  if (lane == 0) { ws[wid] = s; wq[wid] = qq; }
  __syncthreads();
  if (t == 0) {
    ps[d * 8 + sl] = ws[0] + ws[1] + ws[2] + ws[3];
    pq[d * 8 + sl] = wq[0] + wq[1] + wq[2] + wq[3];
  }
}

// ---- BN pass 2: finalize stats, normalize+ReLU+cast, rowsums --------------
__global__ __launch_bounds__(256)
void bn_apply_k(const float* __restrict__ z0, const float* __restrict__ z1,
                const float* __restrict__ gamma, const float* __restrict__ beta,
                const float* __restrict__ ps, const float* __restrict__ pq,
                u16* __restrict__ zb, float* __restrict__ rs)
{
  const int d = blockIdx.x, b = blockIdx.y, t = threadIdx.x;
  const int lane = t & 63, wid = t >> 6;
  __shared__ float bc[2], ws[4];
  if (t == 0) {
    float sum = 0.f, sq = 0.f;
#pragma unroll
    for (int s8 = 0; s8 < 8; ++s8) { sum += ps[d * 8 + s8]; sq += pq[d * 8 + s8]; }
    const float inv_n = 1.f / 25088.f;
    const float mean = sum * inv_n;
    const float var = sq * inv_n - mean * mean;
    const float sc = gamma[d] * rsqrtf(var + 1e-5f);
    bc[0] = sc; bc[1] = fmaf(-mean, sc, beta[d]);
  }
  __syncthreads();
  const float sc = bc[0], sh = bc[1];
  const long off = ((long)b * 256 + d) * 784;
  u16* qp = zb + ((long)b * 256 + d) * 832;
  float rsum = 0.f;
  for (int m = t; m < 832; m += 256) {
    const float v = (m < 784)
        ? fmaxf(fmaf(z0[off + m] + z1[off + m], sc, sh), 0.f) : 0.f;
    qp[m] = f2bf(v);
    rsum += v;
  }
#pragma unroll
  for (int o = 32; o > 0; o >>= 1) rsum += __shfl_down(rsum, o);
  if (lane == 0) ws[wid] = rsum;
  __syncthreads();
  if (t == 0) rs[b * 256 + d] = ws[0] + ws[1] + ws[2] + ws[3];
}

// ---- power iteration v2: j-dim split x4 across 1024 threads ---------------
__global__ __launch_bounds__(1024)
void power_k(const float* __restrict__ cov, float* __restrict__ s,
             float* __restrict__ attn2)
{
  const int b = blockIdx.x, tid = threadIdx.x;
  const int i = tid & 255, g = tid >> 8;        // g in 0..3
  const float* A = cov + (long)b * 65536;
  __shared__ float v[256];
  __shared__ float part[4][256];
  __shared__ float red[4];
  if (g == 0) v[i] = 1.f;
  __syncthreads();
  float lam = 1.f;
  for (int it = 0; it < 10; ++it) {
    float u = 0.f;
    const int jb = g * 64;
#pragma unroll 8
    for (int j = jb; j < jb + 64; ++j) u = fmaf(A[(long)j * 256 + i], v[j], u);
    part[g][i] = u;
    __syncthreads();                            // (1) partials ready
    if (g == 0) {
      u = part[0][i] + part[1][i] + part[2][i] + part[3][i];
      float ss = u * u;
#pragma unroll
      for (int o = 32; o > 0; o >>= 1) ss += __shfl_down(ss, o);
      if ((i & 63) == 0) red[i >> 6] = ss;
    }
    __syncthreads();                            // (2) red ready
    lam = sqrtf(red[0] + red[1] + red[2] + red[3]);
    if (g == 0) v[i] = u / lam;
    __syncthreads();                            // (3) v ready for next iter
  }
  if (tid == 0) { s[b] = 1.8f / lam; attn2[b] = 0.f; }
}

// ---- init: Y0 = split(s*cov); T0 = split(1.5I - 0.5*s*cov)  (Z0 = I) ------
__global__ __launch_bounds__(256)
void init_k(const float* __restrict__ cov, const float* __restrict__ s,
            u16* __restrict__ Yh, u16* __restrict__ Yl,
            u16* __restrict__ Th, u16* __restrict__ Tl)
{
  const int b = blockIdx.y, i = blockIdx.x, j = threadIdx.x;
  const long o = ((long)b * 256 + i) * 256 + j;
  const float a = cov[o] * s[b];
  u16 h = f2bf(a);
  Yh[o] = h; Yl[o] = f2bf(a - bf2f(h));
  float tv = -0.5f * a;
  if (i == j) tv += 1.5f;
  h = f2bf(tv);
  Th[o] = h; Tl[o] = f2bf(tv - bf2f(h));
}

// ---- epilogue: y = (Y/sqrt(s)) * (1 + ||S2||_F/sqrt(s)), triu extract -----
__global__ __launch_bounds__(256)
void out_k(const u16* __restrict__ Yh, const u16* __restrict__ Yl,
           const float* __restrict__ s, const float* __restrict__ attn2,
           float* __restrict__ out)
{
  const int i = blockIdx.x, b = blockIdx.y, j = threadIdx.x;
  if (j < i) return;
  const float inv = rsqrtf(s[b]);
  const float nrm = fmaxf(sqrtf(fmaxf(attn2[b], 0.f)) * inv, 1e-12f);
  const float scv = inv * (1.f + nrm);
  const long o = ((long)b * 256 + i) * 256 + j;
  const long off = (long)b * 32896 + (long)i * 256 - (long)i * (i - 1) / 2 + (j - i);
  out[off] = (bf2f(Yh[o]) + bf2f(Yl[o])) * scv;
}

__global__ __launch_bounds__(256)
void cast_w_k(const float* __restrict__ w, u16* __restrict__ wb)
{
  const int idx = blockIdx.x * 256 + threadIdx.x;
  wb[idx] = f2bf(w[idx]);
}

extern "C" void kernel_launch(void* const* d_in, const int* in_sizes, int n_in,
                              void* d_out, int out_size, void* d_ws, size_t ws_size,
                              hipStream_t stream)
{
  const float* x     = (const float*)d_in[0];   // [32,2048,28,28]
  const float* w     = (const float*)d_in[1];   // [256,2048]
  const float* gamma = (const float*)d_in[2];
  const float* beta  = (const float*)d_in[3];
  float* out = (float*)d_out;

  // ---- workspace: 9 split-pair slots + z0 + z1 + zb + cov + st ------------
  const long PS = 4194304;  // u16 per slot (hi 2,097,152 then lo 2,097,152)
  const long LO = 2097152;
  u16* S[9];
  for (int k = 0; k < 9; ++k) S[k] = (u16*)d_ws + (long)k * PS;
  char* base = (char*)d_ws;
  float* z0  = (float*)(base + 75497472);       // 25,690,112 B
  float* z1  = (float*)(base + 101187584);      // 25,690,112 B
  u16*   zb  = (u16*)(base + 126877696);        // 13,631,488 B
  float* cov = (float*)(base + 140509184);      // 8,388,608 B
  u16*   wbuf = (u16*)(base + 140509184);       // 1 MB, dead before gram
  float* st  = (float*)(base + 148897792);      // ~50 KB of scalars
  float* sv = st, *attn2 = st + 32, *rs = st + 64;
  float* ps = st + 64 + 8192, *pq = ps + 2048;
  u16 *C2 = S[5], *V = S[6], *Ha = S[7], *Hb = S[8];

  const dim3 blk(256);
  const dim3 gP(2, 2, 64);   // dual-task / pair launches: 256 blocks
  const dim3 gT(4, 2, 32);   // 128x64-tile launches:      256 blocks
  const dim3 gE(256, 32);

  // 1) conv: W precast, then K-split M64 GEMM -> z0/z1
  cast_w_k<<<dim3(2048), blk, 0, stream>>>(w, wbuf);
  conv_k<<<dim3(7, 8, 32), blk, 0, stream>>>(wbuf, x, z0, z1);
  // 2) BN: stats pass (2048 blocks) + apply pass (8192 blocks), z = z0+z1
  bn_stats_k<<<dim3(256, 8), blk, 0, stream>>>(z0, z1, ps, pq);
  bn_apply_k<<<dim3(256, 32), blk, 0, stream>>>(z0, z1, gamma, beta, ps, pq, zb, rs);
  // 3) covariance (+ C2 = split(cov) folded into epilogue)
  gram_k<<<dim3(2, 2, 32), blk, 0, stream>>>(zb, rs, cov, C2, C2 + LO);
  // 4) lambda_max (j-split x4); s = 1.8/lam; zero attn2
  power_k<<<dim3(32), dim3(1024), 0, stream>>>(cov, sv, attn2);
  // 5) NS init: Y0 -> S0, T0 -> S1 (Z0 = I => Z1 = T0)
  init_k<<<gE, blk, 0, stream>>>(cov, sv, S[0], S[0] + LO, S[1], S[1] + LO);

  // F1: z<32: Y1 = Y0@T0 -> S2 ; z>=32: V = C2@C2 dual-out Ha = H3
  fuse_k<1><<<gP, blk, 0, stream>>>(
      S[0], S[1], S[2], 1.f, 0.f, 0.f, (const float*)nullptr,
      C2, C2, V, Ha, 1.f, 0.f, 0.f,
      1.f / 40320.f, -1.f / 5040.f, 1.f / 720.f, cov, LO);

  // 6) coupled NS iters 1..7, expm H-chain co-scheduled into iters 1..3.
  int iY = 2, iZ = 1, fa = 0, fb = 3, fc = 4;
  for (int it = 1; it <= 7; ++it) {
    const int iT = fa;
    if (it == 1)        // T1 || Hb = H2 = V@Ha - cov/120 + I/24
      fuse_k<0><<<gP, blk, 0, stream>>>(
          S[iZ], S[iY], S[iT], -0.5f, 0.f, 1.5f, (const float*)nullptr,
          V, Ha, Hb, (u16*)nullptr, 1.f, -1.f / 120.f, 1.f / 24.f,
          0.f, 0.f, 0.f, cov, LO);
    else if (it == 2)   // T2 || Ha = H1 = V@Hb - cov/6 + I/2
      fuse_k<0><<<gP, blk, 0, stream>>>(
          S[iZ], S[iY], S[iT], -0.5f, 0.f, 1.5f, (const float*)nullptr,
          V, Hb, Ha, (u16*)nullptr, 1.f, -1.f / 6.f, 0.5f,
          0.f, 0.f, 0.f, cov, LO);
    else if (it == 3)   // T3 || Hb = H0 = V@Ha - cov + I = e^{-cov}
      fuse_k<0><<<gP, blk, 0, stream>>>(
          S[iZ], S[iY], S[iT], -0.5f, 0.f, 1.5f, (const float*)nullptr,
          V, Ha, Hb, (u16*)nullptr, 1.f, -1.f, 1.f,
          0.f, 0.f, 0.f, cov, LO);
    else                // T4..T7 standalone at full CU coverage
      gemmN64_k<0><<<gT, blk, 0, stream>>>(
          S[iZ], S[iZ] + LO, S[iY], S[iY] + LO, S[iT], S[iT] + LO,
          (const float*)nullptr, -0.5f, 0.f, 1.5f, (float*)nullptr);
    if (it < 7) {
      gemm2_pair_k<<<gP, blk, 0, stream>>>(S[iY], S[iT], S[fb],
                                           S[iT], S[iZ], S[fc], LO);
      const int nY = fb, nZ = fc;
      fa = iY; fb = iZ; fc = iT;
      iY = nY; iZ = nZ;
    } else {            // last iter: Z not needed
      gemmN64_k<0><<<gT, blk, 0, stream>>>(
          S[iY], S[iY] + LO, S[iT], S[iT] + LO, S[fb], S[fb] + LO,
          (const float*)nullptr, 1.f, 0.f, 0.f, (float*)nullptr);
      iY = fb;
    }
  }

  // 7) ||Y@E||_F^2 -> attn2 (atomic, no C write); epilogue
  gemmN64_k<2><<<gT, blk, 0, stream>>>(
      S[iY], S[iY] + LO, Hb, Hb + LO, (u16*)nullptr, (u16*)nullptr,
      (const float*)nullptr, 1.f, 0.f, 0.f, attn2);
  out_k<<<gE, blk, 0, stream>>>(S[iY], S[iY] + LO, sv, attn2, out);
}

// Round 5
// 681.069 us; speedup vs baseline: 1.0905x; 1.0905x over previous
//
#include <hip/hip_runtime.h>

// ============================================================================
// SEB_59201829208446 round 8:
//   - conv_k v4: M=256 (x read ONCE, no m-re-read -> fetch 447->~215 MB),
//     N-tile 64, K-split 2, 512 thr, grid (13,2,32)=832 blocks (6.5 w/SIMD).
//     B-staging: per-thread k-octet gather (8 scalar loads, 256B coalesced)
//     + one conflict-free uint4 LDS write (8 lanes -> 8 XOR chunks).
//   - GEMM family -> 512-thr / 8-wave blocks (was 4 waves/CU):
//     fuse_k & gemm2_pair_k: 128x128 tile, waves 2m x 4n, acc[4][2].
//     gemmN64_k: 128x64 tile, waves 4m x 2n, acc[2][2].
//     gram_k: retiled 128x64 -> grid (4,2,32)=256 blocks (was 128 = half GPU),
//     512 thr, waves 4m x 2n.
//   - BN/power/init/out unchanged from round 7 (742 us; conv 143 us).
// 24 launches.
// ============================================================================

typedef unsigned short u16;
typedef __attribute__((ext_vector_type(8))) short bf16x8;
typedef __attribute__((ext_vector_type(4))) float f32x4;

__device__ __forceinline__ u16 f2bf(float f) {
  unsigned u = __builtin_bit_cast(unsigned, f);
  u += 0x7FFFu + ((u >> 16) & 1u);
  return (u16)(u >> 16);
}
__device__ __forceinline__ float bf2f(u16 h) {
  unsigned u = ((unsigned)h) << 16;
  return __builtin_bit_cast(float, u);
}

// ---------------------------------------------------------------------------
// Core 128x128x256 split-bf16 tile compute, 512 threads (8 waves, 2m x 4n).
// ---------------------------------------------------------------------------
__device__ __forceinline__
void mm_core(const u16* __restrict__ Ah, const u16* __restrict__ Al,
             const u16* __restrict__ Bh, const u16* __restrict__ Bl,
             long boff, int row0, int col0,
             u16 (*lds)[128][8][8], f32x4 acc[4][2])
{
  const int tid = threadIdx.x;
  const int wave = tid >> 6, lane = tid & 63;
  const int wm = wave >> 2, wn = wave & 3;   // 2m x 4n
  const int mL = lane & 15, q = lane >> 4;
  const u16* baseA[2] = {Ah + boff, Al + boff};
  const u16* baseB[2] = {Bh + boff, Bl + boff};

  for (int k0 = 0; k0 < 256; k0 += 64) {
    __syncthreads();
#pragma unroll
    for (int it = 0; it < 8; ++it) {
      const int t = it >> 1;                    // 0:Ah 1:Al 2:Bh 3:Bl
      const int r = ((it & 1) << 9) + tid;      // 0..1023
      const int m = r >> 3, c = r & 7;
      const u16* src = (t < 2 ? baseA[t] : baseB[t - 2])
                     + (long)((t < 2 ? row0 : col0) + m) * 256 + k0 + c * 8;
      *reinterpret_cast<uint4*>(&lds[t][m][c ^ (m & 7)][0]) =
          *reinterpret_cast<const uint4*>(src);
    }
    __syncthreads();
#pragma unroll
    for (int kk = 0; kk < 2; ++kk) {
      bf16x8 ah[4], al[4], bh[2], bl[2];
#pragma unroll
      for (int i = 0; i < 4; ++i) {
        const int ma = wm * 64 + i * 16 + mL;
        const int ca = (kk * 4 + q) ^ (ma & 7);
        ah[i] = *reinterpret_cast<const bf16x8*>(&lds[0][ma][ca][0]);
        al[i] = *reinterpret_cast<const bf16x8*>(&lds[1][ma][ca][0]);
      }
#pragma unroll
      for (int j = 0; j < 2; ++j) {
        const int nb = wn * 32 + j * 16 + mL;
        const int cb = (kk * 4 + q) ^ (nb & 7);
        bh[j] = *reinterpret_cast<const bf16x8*>(&lds[2][nb][cb][0]);
        bl[j] = *reinterpret_cast<const bf16x8*>(&lds[3][nb][cb][0]);
      }
#pragma unroll
      for (int i = 0; i < 4; ++i)
#pragma unroll
        for (int j = 0; j < 2; ++j) {
          acc[i][j] = __builtin_amdgcn_mfma_f32_16x16x32_bf16(ah[i], bh[j], acc[i][j], 0, 0, 0);
          acc[i][j] = __builtin_amdgcn_mfma_f32_16x16x32_bf16(ah[i], bl[j], acc[i][j], 0, 0, 0);
          acc[i][j] = __builtin_amdgcn_mfma_f32_16x16x32_bf16(al[i], bh[j], acc[i][j], 0, 0, 0);
        }
    }
  }
}

// ---------------------------------------------------------------------------
// Dual-task fused GEMM launch (512 thr): z<32 -> task0; z>=32 -> task1.
// MODE0: C = al*(A@B) + b1*cf + dg*I (split out)
// MODE1: C = A@B raw; D = C*hc1 + cf*hc2 + hc3*I
// ---------------------------------------------------------------------------
template<int MB>
__global__ __launch_bounds__(512)
void fuse_k(const u16* __restrict__ A0, const u16* __restrict__ B0, u16* __restrict__ C0,
            float al0, float b10, float dg0, const float* __restrict__ cf0,
            const u16* __restrict__ A1, const u16* __restrict__ B1, u16* __restrict__ C1,
            u16* __restrict__ D1, float al1, float b11, float dg1,
            float hc1, float hc2, float hc3, const float* __restrict__ cf1, long LO)
{
  __shared__ u16 lds[4][128][8][8];
  int z = blockIdx.z;
  const bool hB = (z >= 32);
  const u16 *Ah, *Bh; u16 *C, *D = nullptr;
  float al, b1, dg; const float* cf;
  if (!hB) { Ah = A0; Bh = B0; C = C0; al = al0; b1 = b10; dg = dg0; cf = cf0; }
  else { z -= 32; Ah = A1; Bh = B1; C = C1; D = D1; al = al1; b1 = b11; dg = dg1; cf = cf1; }
  const long boff = (long)z * 65536;
  const int row0 = blockIdx.y * 128, col0 = blockIdx.x * 128;
  const int wave = threadIdx.x >> 6, lane = threadIdx.x & 63;
  const int wm = wave >> 2, wn = wave & 3;
  const int mL = lane & 15, q = lane >> 4;

  f32x4 acc[4][2];
#pragma unroll
  for (int i = 0; i < 4; ++i)
#pragma unroll
    for (int j = 0; j < 2; ++j) acc[i][j] = {0.f, 0.f, 0.f, 0.f};

  mm_core(Ah, Ah + LO, Bh, Bh + LO, boff, row0, col0, lds, acc);

#pragma unroll
  for (int i = 0; i < 4; ++i) {
    const int rbase = row0 + wm * 64 + i * 16 + q * 4;
#pragma unroll
    for (int j = 0; j < 2; ++j) {
      const int cc = col0 + wn * 32 + j * 16 + mL;
#pragma unroll
      for (int rg = 0; rg < 4; ++rg) {
        const int rr = rbase + rg;
        const long o = boff + (long)rr * 256 + cc;
        const float vr = acc[i][j][rg];
        if (MB == 1 && hB) {
          u16 h = f2bf(vr);
          C[o] = h; C[o + LO] = f2bf(vr - bf2f(h));
          float hv = fmaf(vr, hc1, cf[o] * hc2);
          if (rr == cc) hv += hc3;
          h = f2bf(hv);
          D[o] = h; D[o + LO] = f2bf(hv - bf2f(h));
        } else {
          float v = al * vr;
          if (cf) v = fmaf(b1, cf[o], v);
          if (rr == cc) v += dg;
          const u16 h = f2bf(v);
          C[o] = h; C[o + LO] = f2bf(v - bf2f(h));
        }
      }
    }
  }
}

// Fused pair (512 thr): z<32 -> C0 = A0@B0 ; z>=32 -> C1 = A1@B1
__global__ __launch_bounds__(512)
void gemm2_pair_k(const u16* __restrict__ A0, const u16* __restrict__ B0, u16* __restrict__ C0,
                  const u16* __restrict__ A1, const u16* __restrict__ B1, u16* __restrict__ C1,
                  long LO)
{
  __shared__ u16 lds[4][128][8][8];
  int z = blockIdx.z;
  const u16 *Ah, *Bh; u16* Chp;
  if (z < 32) { Ah = A0; Bh = B0; Chp = C0; }
  else { z -= 32; Ah = A1; Bh = B1; Chp = C1; }
  const long boff = (long)z * 65536;
  const int row0 = blockIdx.y * 128, col0 = blockIdx.x * 128;
  const int wave = threadIdx.x >> 6, lane = threadIdx.x & 63;
  const int wm = wave >> 2, wn = wave & 3;
  const int mL = lane & 15, q = lane >> 4;

  f32x4 acc[4][2];
#pragma unroll
  for (int i = 0; i < 4; ++i)
#pragma unroll
    for (int j = 0; j < 2; ++j) acc[i][j] = {0.f, 0.f, 0.f, 0.f};

  mm_core(Ah, Ah + LO, Bh, Bh + LO, boff, row0, col0, lds, acc);

#pragma unroll
  for (int i = 0; i < 4; ++i) {
    const int rbase = row0 + wm * 64 + i * 16 + q * 4;
#pragma unroll
    for (int j = 0; j < 2; ++j) {
      const int cc = col0 + wn * 32 + j * 16 + mL;
#pragma unroll
      for (int rg = 0; rg < 4; ++rg) {
        const long o = boff + (long)(rbase + rg) * 256 + cc;
        const float v = acc[i][j][rg];
        const u16 h = f2bf(v);
        Chp[o] = h; Chp[o + LO] = f2bf(v - bf2f(h));
      }
    }
  }
}

// ---------------------------------------------------------------------------
// 128x64-tile split GEMM, 512 thr (8 waves, 4m x 2n), grid (4,2,32).
// MODE 0: C = alpha*(A@B) + b1*cf + diag*I; MODE 2: Frobenius atomic only.
// ---------------------------------------------------------------------------
template<int MODE>
__global__ __launch_bounds__(512)
void gemmN64_k(const u16* __restrict__ Ah, const u16* __restrict__ Al,
               const u16* __restrict__ Bh, const u16* __restrict__ Bl,
               u16* __restrict__ Ch, u16* __restrict__ Cl,
               const float* __restrict__ cf, float alpha, float b1, float diag,
               float* __restrict__ attn2)
{
  __shared__ u16 ldsA[2][128][8][8];
  __shared__ u16 ldsB[2][64][8][8];
  const long boff = (long)blockIdx.z * 65536;
  const int row0 = blockIdx.y * 128, col0 = blockIdx.x * 64;
  const int tid = threadIdx.x;
  const int wave = tid >> 6, lane = tid & 63;
  const int wm = wave >> 1, wn = wave & 1;    // 4m x 2n
  const int mL = lane & 15, q = lane >> 4;
  const u16* baseA[2] = {Ah + boff, Al + boff};
  const u16* baseB[2] = {Bh + boff, Bl + boff};

  f32x4 acc[2][2];
#pragma unroll
  for (int i = 0; i < 2; ++i)
#pragma unroll
    for (int j = 0; j < 2; ++j) acc[i][j] = {0.f, 0.f, 0.f, 0.f};

  for (int k0 = 0; k0 < 256; k0 += 64) {
    __syncthreads();
#pragma unroll
    for (int it = 0; it < 4; ++it) {           // A: 2 planes x 2 its
      const int t = it >> 1;
      const int r = ((it & 1) << 9) + tid;
      const int m = r >> 3, c = r & 7;
      *reinterpret_cast<uint4*>(&ldsA[t][m][c ^ (m & 7)][0]) =
          *reinterpret_cast<const uint4*>(baseA[t] + (long)(row0 + m) * 256 + k0 + c * 8);
    }
#pragma unroll
    for (int it = 0; it < 2; ++it) {           // B: 2 planes x 1 it
      const int m = tid >> 3, c = tid & 7;
      *reinterpret_cast<uint4*>(&ldsB[it][m][c ^ (m & 7)][0]) =
          *reinterpret_cast<const uint4*>(baseB[it] + (long)(col0 + m) * 256 + k0 + c * 8);
    }
    __syncthreads();
#pragma unroll
    for (int kk = 0; kk < 2; ++kk) {
      bf16x8 ah[2], alo[2], bh[2], bl[2];
#pragma unroll
      for (int i = 0; i < 2; ++i) {
        const int ma = wm * 32 + i * 16 + mL;
        const int ca = (kk * 4 + q) ^ (ma & 7);
        ah[i]  = *reinterpret_cast<const bf16x8*>(&ldsA[0][ma][ca][0]);
        alo[i] = *reinterpret_cast<const bf16x8*>(&ldsA[1][ma][ca][0]);
      }
#pragma unroll
      for (int j = 0; j < 2; ++j) {
        const int nb = wn * 32 + j * 16 + mL;
        const int cb = (kk * 4 + q) ^ (nb & 7);
        bh[j] = *reinterpret_cast<const bf16x8*>(&ldsB[0][nb][cb][0]);
        bl[j] = *reinterpret_cast<const bf16x8*>(&ldsB[1][nb][cb][0]);
      }
#pragma unroll
      for (int i = 0; i < 2; ++i)
#pragma unroll
        for (int j = 0; j < 2; ++j) {
          acc[i][j] = __builtin_amdgcn_mfma_f32_16x16x32_bf16(ah[i],  bh[j], acc[i][j], 0, 0, 0);
          acc[i][j] = __builtin_amdgcn_mfma_f32_16x16x32_bf16(ah[i],  bl[j], acc[i][j], 0, 0, 0);
          acc[i][j] = __builtin_amdgcn_mfma_f32_16x16x32_bf16(alo[i], bh[j], acc[i][j], 0, 0, 0);
        }
    }
  }

  if (MODE == 2) {
    float ssum = 0.f;
#pragma unroll
    for (int i = 0; i < 2; ++i)
#pragma unroll
      for (int j = 0; j < 2; ++j)
#pragma unroll
        for (int rg = 0; rg < 4; ++rg) ssum = fmaf(acc[i][j][rg], acc[i][j][rg], ssum);
#pragma unroll
    for (int o = 32; o > 0; o >>= 1) ssum += __shfl_down(ssum, o);
    __syncthreads();
    float* red = (float*)&ldsA[0][0][0][0];
    if (lane == 0) red[wave] = ssum;
    __syncthreads();
    if (tid == 0) {
      float t8 = 0.f;
#pragma unroll
      for (int wv = 0; wv < 8; ++wv) t8 += red[wv];
      atomicAdd(attn2 + blockIdx.z, t8);
    }
    return;
  }

#pragma unroll
  for (int i = 0; i < 2; ++i) {
    const int rbase = row0 + wm * 32 + i * 16 + q * 4;
#pragma unroll
    for (int j = 0; j < 2; ++j) {
      const int cc = col0 + wn * 32 + j * 16 + mL;
#pragma unroll
      for (int rg = 0; rg < 4; ++rg) {
        const int rr = rbase + rg;
        const long o = boff + (long)rr * 256 + cc;
        float v = alpha * acc[i][j][rg];
        if (cf) v = fmaf(b1, cf[o], v);
        if (rr == cc) v += diag;
        const u16 h = f2bf(v);
        Ch[o] = h; Cl[o] = f2bf(v - bf2f(h));
      }
    }
  }
}

// ---------------------------------------------------------------------------
// conv1x1 v4: z[b] = W(256x2048) @ x_b(2048x784). M=256 (x read once),
// N-tile 64, K-split 2, 512 thr, grid (13,2,32)=832 blocks. 40 KB LDS.
// ---------------------------------------------------------------------------
__global__ __launch_bounds__(512)
void conv_k(const u16* __restrict__ wb, const float* __restrict__ x,
            float* __restrict__ z0, float* __restrict__ z1)
{
  __shared__ u16 ldsA[256][8][8];   // 32 KB: all 256 W rows
  __shared__ u16 ldsB[64][8][8];    // 8 KB: x cols n0..n0+63 (as rows)
  const int tid = threadIdx.x;
  const int b = blockIdx.z;
  const int n0 = blockIdx.x * 64;
  const int ks = blockIdx.y;
  const int kb0 = ks * 1024;
  const int wave = tid >> 6, lane = tid & 63;
  const int wm = wave >> 1, wn = wave & 1;    // 4m x 2n
  const int mL = lane & 15, q = lane >> 4;
  const float* xb = x + (long)b * 2048 * 784;
  float* zp = (ks == 0 ? z0 : z1);

  f32x4 acc[4][2];
#pragma unroll
  for (int i = 0; i < 4; ++i)
#pragma unroll
    for (int j = 0; j < 2; ++j) acc[i][j] = {0.f, 0.f, 0.f, 0.f};

  const int kc = tid >> 6, nc = tid & 63;     // kc = k-octet 0..7, nc = n 0..63
  const int gn = n0 + nc;
  const bool nok = (gn < 784);

  for (int k0 = 0; k0 < 1024; k0 += 64) {
    const int kg = kb0 + k0;
    __syncthreads();
    // A: 256 rows x 8 chunks = 2048 uint4 slots; 4 per thread (from wb, L2)
#pragma unroll
    for (int it = 0; it < 4; ++it) {
      const int g = it * 512 + tid;
      const int m = g >> 3, c = g & 7;
      *reinterpret_cast<uint4*>(&ldsA[m][c ^ (m & 7)][0]) =
          *reinterpret_cast<const uint4*>(wb + (long)m * 2048 + kg + c * 8);
    }
    // B: thread gathers its k-octet (8 scalar loads, 256B coalesced across
    // lanes) for one n; single conflict-free uint4 LDS write.
    {
      float vv[8];
#pragma unroll
      for (int jk = 0; jk < 8; ++jk)
        vv[jk] = nok ? xb[(long)(kg + kc * 8 + jk) * 784 + gn] : 0.f;
      ushort4 ua, ub;
      ua.x = f2bf(vv[0]); ua.y = f2bf(vv[1]); ua.z = f2bf(vv[2]); ua.w = f2bf(vv[3]);
      ub.x = f2bf(vv[4]); ub.y = f2bf(vv[5]); ub.z = f2bf(vv[6]); ub.w = f2bf(vv[7]);
      const int ch = kc ^ (nc & 7);
      *reinterpret_cast<ushort4*>(&ldsB[nc][ch][0]) = ua;
      *reinterpret_cast<ushort4*>(&ldsB[nc][ch][4]) = ub;
    }
    __syncthreads();
#pragma unroll
    for (int kk = 0; kk < 2; ++kk) {
      bf16x8 af[4], bfv[2];
#pragma unroll
      for (int i = 0; i < 4; ++i) {
        const int ma = wm * 64 + i * 16 + mL;
        af[i] = *reinterpret_cast<const bf16x8*>(&ldsA[ma][(kk * 4 + q) ^ (ma & 7)][0]);
      }
#pragma unroll
      for (int j = 0; j < 2; ++j) {
        const int nb = wn * 32 + j * 16 + mL;
        bfv[j] = *reinterpret_cast<const bf16x8*>(&ldsB[nb][(kk * 4 + q) ^ (nb & 7)][0]);
      }
#pragma unroll
      for (int i = 0; i < 4; ++i)
#pragma unroll
        for (int j = 0; j < 2; ++j)
          acc[i][j] = __builtin_amdgcn_mfma_f32_16x16x32_bf16(af[i], bfv[j], acc[i][j], 0, 0, 0);
    }
  }
#pragma unroll
  for (int i = 0; i < 4; ++i) {
    const int rbase = wm * 64 + i * 16 + q * 4;
#pragma unroll
    for (int j = 0; j < 2; ++j) {
      const int cc = n0 + wn * 32 + j * 16 + mL;
      if (cc >= 784) continue;
#pragma unroll
      for (int rg = 0; rg < 4; ++rg)
        zp[((long)b * 256 + rbase + rg) * 784 + cc] = acc[i][j][rg];
    }
  }
}

// ---------------------------------------------------------------------------
// Gram (512 thr): cov[b] = (1/784) zb@zb^T - mu mu^T; C2 = split(cov).
// Tile 128x64, grid (4,2,32)=256 blocks. K=832 (13 rounds).
// ---------------------------------------------------------------------------
__global__ __launch_bounds__(512)
void gram_k(const u16* __restrict__ zb, const float* __restrict__ rs,
            float* __restrict__ cov, u16* __restrict__ C2h, u16* __restrict__ C2l)
{
  __shared__ u16 ldsA[128][8][8];   // 16 KB
  __shared__ u16 ldsB[64][8][8];    // 8 KB
  const int tid = threadIdx.x;
  const int b = blockIdx.z;
  const int col0 = blockIdx.x * 64, row0 = blockIdx.y * 128;
  const int wave = tid >> 6, lane = tid & 63;
  const int wm = wave >> 1, wn = wave & 1;    // 4m x 2n
  const int mL = lane & 15, q = lane >> 4;
  const u16* zbb = zb + (long)b * 256 * 832;

  f32x4 acc[2][2];
#pragma unroll
  for (int i = 0; i < 2; ++i)
#pragma unroll
    for (int j = 0; j < 2; ++j) acc[i][j] = {0.f, 0.f, 0.f, 0.f};

  for (int k0 = 0; k0 < 832; k0 += 64) {
    __syncthreads();
#pragma unroll
    for (int it = 0; it < 2; ++it) {           // A: 1024 slots
      const int r = it * 512 + tid;
      const int m = r >> 3, c = r & 7;
      *reinterpret_cast<uint4*>(&ldsA[m][c ^ (m & 7)][0]) =
          *reinterpret_cast<const uint4*>(zbb + (long)(row0 + m) * 832 + k0 + c * 8);
    }
    {                                          // B: 512 slots
      const int m = tid >> 3, c = tid & 7;
      *reinterpret_cast<uint4*>(&ldsB[m][c ^ (m & 7)][0]) =
          *reinterpret_cast<const uint4*>(zbb + (long)(col0 + m) * 832 + k0 + c * 8);
    }
    __syncthreads();
#pragma unroll
    for (int kk = 0; kk < 2; ++kk) {
      bf16x8 af[2], bfv[2];
#pragma unroll
      for (int i = 0; i < 2; ++i) {
        const int ma = wm * 32 + i * 16 + mL;
        af[i] = *reinterpret_cast<const bf16x8*>(&ldsA[ma][(kk * 4 + q) ^ (ma & 7)][0]);
      }
#pragma unroll
      for (int j = 0; j < 2; ++j) {
        const int nb = wn * 32 + j * 16 + mL;
        bfv[j] = *reinterpret_cast<const bf16x8*>(&ldsB[nb][(kk * 4 + q) ^ (nb & 7)][0]);
      }
#pragma unroll
      for (int i = 0; i < 2; ++i)
#pragma unroll
        for (int j = 0; j < 2; ++j)
          acc[i][j] = __builtin_amdgcn_mfma_f32_16x16x32_bf16(af[i], bfv[j], acc[i][j], 0, 0, 0);
    }
  }
  const float inv_m = 1.f / 784.f;
#pragma unroll
  for (int i = 0; i < 2; ++i) {
    const int rr0 = row0 + wm * 32 + i * 16 + q * 4;
#pragma unroll
    for (int j = 0; j < 2; ++j) {
      const int cc = col0 + wn * 32 + j * 16 + mL;
      const float mu_c = rs[b * 256 + cc] * inv_m;
#pragma unroll
      for (int rg = 0; rg < 4; ++rg) {
        const int rr = rr0 + rg;
        const float mu_r = rs[b * 256 + rr] * inv_m;
        const long o = ((long)b * 256 + rr) * 256 + cc;
        const float cv = fmaf(acc[i][j][rg], inv_m, -mu_r * mu_c);
        cov[o] = cv;
        const u16 h = f2bf(cv);
        C2h[o] = h; C2l[o] = f2bf(cv - bf2f(h));
      }
    }
  }
}

// ---- BN pass 1: partial sums/sumsq per (channel, batch-slice of 4) --------
__global__ __launch_bounds__(256)
void bn_stats_k(const float* __restrict__ z0, const float* __restrict__ z1,
                float* __restrict__ ps, float* __restrict__ pq)
{
  const int d = blockIdx.x, sl = blockIdx.y, t = threadIdx.x;
  const int lane = t & 63, wid = t >> 6;
  __shared__ float ws[4], wq[4];
  float s = 0.f, qq = 0.f;
  for (int b = sl * 4; b < sl * 4 + 4; ++b) {
    const long off = ((long)b * 256 + d) * 784;
    for (int m = t; m < 784; m += 256) {
      const float v = z0[off + m] + z1[off + m];
      s += v; qq = fmaf(v, v, qq);
    }
  }
#pragma unroll
  for (int o = 32; o > 0; o >>= 1) { s += __shfl_down(s, o); qq += __shfl_down(qq, o); }
  if (lane == 0) { ws[wid] = s; wq[wid] = qq; }
  __syncthreads();
  if (t == 0) {
    ps[d * 8 + sl] = ws[0] + ws[1] + ws[2] + ws[3];
    pq[d * 8 + sl] = wq[0] + wq[1] + wq[2] + wq[3];
  }
}

// ---- BN pass 2: finalize stats, normalize+ReLU+cast, rowsums --------------
__global__ __launch_bounds__(256)
void bn_apply_k(const float* __restrict__ z0, const float* __restrict__ z1,
                const float* __restrict__ gamma, const float* __restrict__ beta,
                const float* __restrict__ ps, const float* __restrict__ pq,
                u16* __restrict__ zb, float* __restrict__ rs)
{
  const int d = blockIdx.x, b = blockIdx.y, t = threadIdx.x;
  const int lane = t & 63, wid = t >> 6;
  __shared__ float bc[2], ws[4];
  if (t == 0) {
    float sum = 0.f, sq = 0.f;
#pragma unroll
    for (int s8 = 0; s8 < 8; ++s8) { sum += ps[d * 8 + s8]; sq += pq[d * 8 + s8]; }
    const float inv_n = 1.f / 25088.f;
    const float mean = sum * inv_n;
    const float var = sq * inv_n - mean * mean;
    const float sc = gamma[d] * rsqrtf(var + 1e-5f);
    bc[0] = sc; bc[1] = fmaf(-mean, sc, beta[d]);
  }
  __syncthreads();
  const float sc = bc[0], sh = bc[1];
  const long off = ((long)b * 256 + d) * 784;
  u16* qp = zb + ((long)b * 256 + d) * 832;
  float rsum = 0.f;
  for (int m = t; m < 832; m += 256) {
    const float v = (m < 784)
        ? fmaxf(fmaf(z0[off + m] + z1[off + m], sc, sh), 0.f) : 0.f;
    qp[m] = f2bf(v);
    rsum += v;
  }
#pragma unroll
  for (int o = 32; o > 0; o >>= 1) rsum += __shfl_down(rsum, o);
  if (lane == 0) ws[wid] = rsum;
  __syncthreads();
  if (t == 0) rs[b * 256 + d] = ws[0] + ws[1] + ws[2] + ws[3];
}

// ---- power iteration: j-dim split x4 across 1024 threads ------------------
__global__ __launch_bounds__(1024)
void power_k(const float* __restrict__ cov, float* __restrict__ s,
             float* __restrict__ attn2)
{
  const int b = blockIdx.x, tid = threadIdx.x;
  const int i = tid & 255, g = tid >> 8;        // g in 0..3
  const float* A = cov + (long)b * 65536;
  __shared__ float v[256];
  __shared__ float part[4][256];
  __shared__ float red[4];
  if (g == 0) v[i] = 1.f;
  __syncthreads();
  float lam = 1.f;
  for (int it = 0; it < 10; ++it) {
    float u = 0.f;
    const int jb = g * 64;
#pragma unroll 8
    for (int j = jb; j < jb + 64; ++j) u = fmaf(A[(long)j * 256 + i], v[j], u);
    part[g][i] = u;
    __syncthreads();
    if (g == 0) {
      u = part[0][i] + part[1][i] + part[2][i] + part[3][i];
      float ss = u * u;
#pragma unroll
      for (int o = 32; o > 0; o >>= 1) ss += __shfl_down(ss, o);
      if ((i & 63) == 0) red[i >> 6] = ss;
    }
    __syncthreads();
    lam = sqrtf(red[0] + red[1] + red[2] + red[3]);
    if (g == 0) v[i] = u / lam;
    __syncthreads();
  }
  if (tid == 0) { s[b] = 1.8f / lam; attn2[b] = 0.f; }
}

// ---- init: Y0 = split(s*cov); T0 = split(1.5I - 0.5*s*cov)  (Z0 = I) ------
__global__ __launch_bounds__(256)
void init_k(const float* __restrict__ cov, const float* __restrict__ s,
            u16* __restrict__ Yh, u16* __restrict__ Yl,
            u16* __restrict__ Th, u16* __restrict__ Tl)
{
  const int b = blockIdx.y, i = blockIdx.x, j = threadIdx.x;
  const long o = ((long)b * 256 + i) * 256 + j;
  const float a = cov[o] * s[b];
  u16 h = f2bf(a);
  Yh[o] = h; Yl[o] = f2bf(a - bf2f(h));
  float tv = -0.5f * a;
  if (i == j) tv += 1.5f;
  h = f2bf(tv);
  Th[o] = h; Tl[o] = f2bf(tv - bf2f(h));
}

// ---- epilogue: y = (Y/sqrt(s)) * (1 + ||S2||_F/sqrt(s)), triu extract -----
__global__ __launch_bounds__(256)
void out_k(const u16* __restrict__ Yh, const u16* __restrict__ Yl,
           const float* __restrict__ s, const float* __restrict__ attn2,
           float* __restrict__ out)
{
  const int i = blockIdx.x, b = blockIdx.y, j = threadIdx.x;
  if (j < i) return;
  const float inv = rsqrtf(s[b]);
  const float nrm = fmaxf(sqrtf(fmaxf(attn2[b], 0.f)) * inv, 1e-12f);
  const float scv = inv * (1.f + nrm);
  const long o = ((long)b * 256 + i) * 256 + j;
  const long off = (long)b * 32896 + (long)i * 256 - (long)i * (i - 1) / 2 + (j - i);
  out[off] = (bf2f(Yh[o]) + bf2f(Yl[o])) * scv;
}

__global__ __launch_bounds__(256)
void cast_w_k(const float* __restrict__ w, u16* __restrict__ wb)
{
  const int idx = blockIdx.x * 256 + threadIdx.x;
  wb[idx] = f2bf(w[idx]);
}

extern "C" void kernel_launch(void* const* d_in, const int* in_sizes, int n_in,
                              void* d_out, int out_size, void* d_ws, size_t ws_size,
                              hipStream_t stream)
{
  const float* x     = (const float*)d_in[0];   // [32,2048,28,28]
  const float* w     = (const float*)d_in[1];   // [256,2048]
  const float* gamma = (const float*)d_in[2];
  const float* beta  = (const float*)d_in[3];
  float* out = (float*)d_out;

  // ---- workspace: 9 split-pair slots + z0 + z1 + zb + cov + st ------------
  const long PS = 4194304;  // u16 per slot (hi 2,097,152 then lo 2,097,152)
  const long LO = 2097152;
  u16* S[9];
  for (int k = 0; k < 9; ++k) S[k] = (u16*)d_ws + (long)k * PS;
  char* base = (char*)d_ws;
  float* z0  = (float*)(base + 75497472);       // 25,690,112 B
  float* z1  = (float*)(base + 101187584);      // 25,690,112 B
  u16*   zb  = (u16*)(base + 126877696);        // 13,631,488 B
  float* cov = (float*)(base + 140509184);      // 8,388,608 B
  u16*   wbuf = (u16*)(base + 140509184);       // 1 MB, dead before gram
  float* st  = (float*)(base + 148897792);      // ~50 KB of scalars
  float* sv = st, *attn2 = st + 32, *rs = st + 64;
  float* ps = st + 64 + 8192, *pq = ps + 2048;
  u16 *C2 = S[5], *V = S[6], *Ha = S[7], *Hb = S[8];

  const dim3 blk(256), blk5(512);
  const dim3 gP(2, 2, 64);   // dual-task / pair launches: 256 blocks x 512thr
  const dim3 gT(4, 2, 32);   // 128x64-tile launches:      256 blocks x 512thr
  const dim3 gE(256, 32);

  // 1) conv: W precast, then M256/Ksplit2 GEMM -> z0/z1 (x read once)
  cast_w_k<<<dim3(2048), blk, 0, stream>>>(w, wbuf);
  conv_k<<<dim3(13, 2, 32), blk5, 0, stream>>>(wbuf, x, z0, z1);
  // 2) BN: stats pass (2048 blocks) + apply pass (8192 blocks), z = z0+z1
  bn_stats_k<<<dim3(256, 8), blk, 0, stream>>>(z0, z1, ps, pq);
  bn_apply_k<<<dim3(256, 32), blk, 0, stream>>>(z0, z1, gamma, beta, ps, pq, zb, rs);
  // 3) covariance 128x64 tiles (+ C2 split folded)
  gram_k<<<gT, blk5, 0, stream>>>(zb, rs, cov, C2, C2 + LO);
  // 4) lambda_max; s = 1.8/lam; zero attn2
  power_k<<<dim3(32), dim3(1024), 0, stream>>>(cov, sv, attn2);
  // 5) NS init: Y0 -> S0, T0 -> S1 (Z0 = I => Z1 = T0)
  init_k<<<gE, blk, 0, stream>>>(cov, sv, S[0], S[0] + LO, S[1], S[1] + LO);

  // F1: z<32: Y1 = Y0@T0 -> S2 ; z>=32: V = C2@C2 dual-out Ha = H3
  fuse_k<1><<<gP, blk5, 0, stream>>>(
      S[0], S[1], S[2], 1.f, 0.f, 0.f, (const float*)nullptr,
      C2, C2, V, Ha, 1.f, 0.f, 0.f,
      1.f / 40320.f, -1.f / 5040.f, 1.f / 720.f, cov, LO);

  // 6) coupled NS iters 1..7, expm H-chain co-scheduled into iters 1..3.
  int iY = 2, iZ = 1, fa = 0, fb = 3, fc = 4;
  for (int it = 1; it <= 7; ++it) {
    const int iT = fa;
    if (it == 1)        // T1 || Hb = H2 = V@Ha - cov/120 + I/24
      fuse_k<0><<<gP, blk5, 0, stream>>>(
          S[iZ], S[iY], S[iT], -0.5f, 0.f, 1.5f, (const float*)nullptr,
          V, Ha, Hb, (u16*)nullptr, 1.f, -1.f / 120.f, 1.f / 24.f,
          0.f, 0.f, 0.f, cov, LO);
    else if (it == 2)   // T2 || Ha = H1 = V@Hb - cov/6 + I/2
      fuse_k<0><<<gP, blk5, 0, stream>>>(
          S[iZ], S[iY], S[iT], -0.5f, 0.f, 1.5f, (const float*)nullptr,
          V, Hb, Ha, (u16*)nullptr, 1.f, -1.f / 6.f, 0.5f,
          0.f, 0.f, 0.f, cov, LO);
    else if (it == 3)   // T3 || Hb = H0 = V@Ha - cov + I = e^{-cov}
      fuse_k<0><<<gP, blk5, 0, stream>>>(
          S[iZ], S[iY], S[iT], -0.5f, 0.f, 1.5f, (const float*)nullptr,
          V, Ha, Hb, (u16*)nullptr, 1.f, -1.f, 1.f,
          0.f, 0.f, 0.f, cov, LO);
    else                // T4..T7 standalone at full CU coverage
      gemmN64_k<0><<<gT, blk5, 0, stream>>>(
          S[iZ], S[iZ] + LO, S[iY], S[iY] + LO, S[iT], S[iT] + LO,
          (const float*)nullptr, -0.5f, 0.f, 1.5f, (float*)nullptr);
    if (it < 7) {
      gemm2_pair_k<<<gP, blk5, 0, stream>>>(S[iY], S[iT], S[fb],
                                            S[iT], S[iZ], S[fc], LO);
      const int nY = fb, nZ = fc;
      fa = iY; fb = iZ; fc = iT;
      iY = nY; iZ = nZ;
    } else {            // last iter: Z not needed
      gemmN64_k<0><<<gT, blk5, 0, stream>>>(
          S[iY], S[iY] + LO, S[iT], S[iT] + LO, S[fb], S[fb] + LO,
          (const float*)nullptr, 1.f, 0.f, 0.f, (float*)nullptr);
      iY = fb;
    }
  }

  // 7) ||Y@E||_F^2 -> attn2 (atomic, no C write); epilogue
  gemmN64_k<2><<<gT, blk5, 0, stream>>>(
      S[iY], S[iY] + LO, Hb, Hb + LO, (u16*)nullptr, (u16*)nullptr,
      (const float*)nullptr, 1.f, 0.f, 0.f, attn2);
  out_k<<<gE, blk, 0, stream>>>(S[iY], S[iY] + LO, sv, attn2, out);
}